// Round 4
// baseline (1130.098 us; speedup 1.0000x reference)
//
#include <hip/hip_runtime.h>
#include <hip/hip_bf16.h>

// ---------------------------------------------------------------------------
// 2-layer LSTM decoder, B=64, T=25, H=2048, IN=OUT=66, hardtanh feedback.
// v4: FC folded into L1 epilogue (per-block partial + atomicAdd) and L0
// prologue (bias+hardtanh+stage x in LDS); cast+init merged; PF=3 prefetch.
// 52 launches total (was 77).
// ---------------------------------------------------------------------------

typedef short bfrag  __attribute__((ext_vector_type(8)));   // 8 bf16 (4 VGPR)
typedef float accv   __attribute__((ext_vector_type(4)));   // 4 fp32 acc
typedef float vfloat4 __attribute__((ext_vector_type(4)));
typedef unsigned short usvec8 __attribute__((ext_vector_type(8)));

#define LD8(p) (*(const bfrag*)(p))

__device__ __forceinline__ unsigned short f2bf(float x) {
    unsigned int u = __float_as_uint(x);
    unsigned int r = u + 0x7FFFu + ((u >> 16) & 1u);   // RTNE
    return (unsigned short)(r >> 16);
}

// Activation fragment layout ("Ap", KC chunks of 32 k-elements):
//   (b, k) -> [((b>>4)*KC + (k>>5))*512 + (((k>>3)&3)*16 + (b&15))*8 + (k&7)]
__device__ __forceinline__ int ap_idx(int b, int j, int KC) {
    return (((b >> 4) * KC + (j >> 5)) << 9) + ((((j >> 3) & 3) * 16 + (b & 15)) << 3) + (j & 7);
}

// Weight fragment layout ("Bp"): n-tile (jb,p) holds rows
//   row = (2p + (n>>3))*2048 + jb*8 + (n&7),  n = lane&15
//   element at [((jb*2+p)*KC + kc)*512 + lane*8 + j],  k = kc*32 + (lane>>4)*8 + j

// ------------------- combined weight cast + state init ---------------------
__global__ __launch_bounds__(256) void prep(
        const float* __restrict__ s0, const float* __restrict__ s1, const float* __restrict__ s2,
        unsigned short* __restrict__ d0, unsigned short* __restrict__ d1, unsigned short* __restrict__ d2,
        const float* __restrict__ inputs, const float* __restrict__ hiddens,
        const float* __restrict__ cells,  const float* __restrict__ wih0,
        unsigned short* __restrict__ wih0p,
        unsigned short* __restrict__ h0, unsigned short* __restrict__ h1,
        float* __restrict__ c0, float* __restrict__ c1,
        unsigned short* __restrict__ xb,
        float* __restrict__ bsum0, float* __restrict__ bsum1,
        const float* __restrict__ bih0, const float* __restrict__ bhh0,
        const float* __restrict__ bih1, const float* __restrict__ bhh1,
        float* __restrict__ ows) {
    int bid = blockIdx.x;
    if (bid < 24576) {                       // big-weight cast+permute
        unsigned int tid = bid * 256 + threadIdx.x;     // 0 .. 6291455
        unsigned int a = tid >> 21;                     // 2097152 frags per matrix
        unsigned int r = tid & 2097151u;
        const float* src = (a == 0) ? s0 : (a == 1) ? s1 : s2;
        unsigned short* dst = (a == 0) ? d0 : (a == 1) ? d1 : d2;
        unsigned int lane = r & 63u;
        unsigned int kc   = (r >> 6) & 63u;
        unsigned int p    = (r >> 12) & 1u;
        unsigned int jb   = r >> 13;
        unsigned int n = lane & 15u, quad = lane >> 4;
        unsigned int row = (2u * p + (n >> 3)) * 2048u + jb * 8u + (n & 7u);
        unsigned int k0  = kc * 32u + quad * 8u;
        const float* sp = src + (size_t)row * 2048 + k0;
        vfloat4 v0 = *(const vfloat4*)sp;
        vfloat4 v1 = *(const vfloat4*)(sp + 4);
        usvec8 u = { f2bf(v0.x), f2bf(v0.y), f2bf(v0.z), f2bf(v0.w),
                     f2bf(v1.x), f2bf(v1.y), f2bf(v1.z), f2bf(v1.w) };
        *(usvec8*)(dst + (size_t)r * 8) = u;
        return;
    }
    int i = (bid - 24576) * 256 + threadIdx.x;
    if (i < 786432) {                        // Wih0 pad-permute: [8192][66] -> Bp KC=3
        int jo = i & 7, lane = (i >> 3) & 63;
        int t2 = i >> 9, kc = t2 % 3, t3 = t2 / 3, p = t3 & 1, jb = t3 >> 1;
        int n = lane & 15, quad = lane >> 4;
        int row = (2 * p + (n >> 3)) * 2048 + jb * 8 + (n & 7);
        int k = kc * 32 + quad * 8 + jo;
        wih0p[i] = (k < 66) ? f2bf(wih0[row * 66 + k]) : (unsigned short)0;
        return;
    }
    i -= 786432;
    if (i < 131072) { int b = i >> 11, j = i & 2047; h0[ap_idx(b, j, 64)] = f2bf(hiddens[i]); return; }
    i -= 131072;
    if (i < 131072) { int b = i >> 11, j = i & 2047; h1[ap_idx(b, j, 64)] = f2bf(hiddens[131072 + i]); return; }
    i -= 131072;
    if (i < 131072) { int b = i >> 11, j = i & 2047; c0[(j >> 3) * 512 + b * 8 + (j & 7)] = cells[i]; return; }
    i -= 131072;
    if (i < 131072) { int b = i >> 11, j = i & 2047; c1[(j >> 3) * 512 + b * 8 + (j & 7)] = cells[131072 + i]; return; }
    i -= 131072;
    if (i < 6144) {                          // x pad-permute -> Ap KC=3
        int jo = i & 7, lane = (i >> 3) & 63;
        int t2 = i >> 9, kc = t2 % 3, m = t2 / 3;
        int b = m * 16 + (lane & 15);
        int k = kc * 32 + (lane >> 4) * 8 + jo;
        xb[i] = (k < 66) ? f2bf(inputs[b * 66 + k]) : (unsigned short)0;
        return;
    }
    i -= 6144;
    if (i < 8192) { bsum0[i] = bih0[i] + bhh0[i]; return; }
    i -= 8192;
    if (i < 8192) { bsum1[i] = bih1[i] + bhh1[i]; return; }
    i -= 8192;
    if (i < 105600) { ows[i] = 0.f; }        // 25 x [66][64] FC accumulators
}

// --------------------------- layer 0 ---------------------------------------
// grid 256 x 512. Prologue (t>0): finalize previous FC partials -> x (LDS) +
// write out[t-1]. Main: source1 = x (3 chunks, waves 0-2), source2 = h0 prev.
__global__ __launch_bounds__(512, 2) void lstm_l0(
        const unsigned short* __restrict__ xb,   // Ap KC=3 (t=0 only)
        const unsigned short* __restrict__ Bp1,  // wih0p, Bp KC=3
        const unsigned short* __restrict__ Ap2,  // h0 prev, Ap KC=64
        const unsigned short* __restrict__ Bp2,  // whh0p, Bp KC=64
        const float* __restrict__ bsum,
        const float* __restrict__ ows,           // out_ws[t-1] ([66][64]) or null
        const float* __restrict__ fcb,
        float* __restrict__ outg, int tprev,
        float* __restrict__ c_state,
        unsigned short* __restrict__ h_out) {
    __shared__ float gsm[8][64][32];             // 64 KB, XOR-swizzled
    __shared__ unsigned short xsm[64][104];      // x staged bf16, padded cols
    int tid = threadIdx.x, lane = tid & 63, w = tid >> 6;
    int jb = blockIdx.x;

    if (ows) {
        for (int i = tid; i < (64 * 104) / 2; i += 512) ((unsigned int*)xsm)[i] = 0u;
        __syncthreads();
        for (int idx = tid; idx < 4224; idx += 512) {
            int o = idx >> 6, b = idx & 63;
            float v = ows[idx] + fcb[o];
            v = fminf(1.f, fmaxf(-1.f, v));
            if (jb == 0) outg[((size_t)b * 25 + tprev) * 66 + o] = v;
            xsm[b][o] = f2bf(v);
        }
        __syncthreads();
    }

    constexpr int PF = 3, NC = 8;
    accv acc[4][2] = {};

    // ---- source 1 (x @ Wih0^T), waves 0..2 only
    bfrag xa[4], xw[2];
    bool s1 = (w < 3);
    if (s1) {
        const unsigned short* bp = Bp1 + (((size_t)(2 * jb) * 3 + w) << 9) + lane * 8;
        xw[0] = LD8(bp);
        xw[1] = LD8(bp + (3 << 9));
        if (ows) {
            int n15 = lane & 15, k0 = w * 32 + (lane >> 4) * 8;
            #pragma unroll
            for (int mi = 0; mi < 4; ++mi) xa[mi] = *(const bfrag*)&xsm[mi * 16 + n15][k0];
        } else {
            #pragma unroll
            for (int mi = 0; mi < 4; ++mi) xa[mi] = LD8(xb + (((size_t)mi * 3 + w) << 9) + lane * 8);
        }
    }

    // ---- source 2 (h0 @ Whh0^T), 8 chunks per wave, PF=3
    const unsigned short* a2 = Ap2 + ((size_t)w << 9) + lane * 8;
    const unsigned short* b2 = Bp2 + (((size_t)(2 * jb) * 64 + w) << 9) + lane * 8;
    bfrag fA[PF][4], fB[PF][2];
    auto issue = [&](int i) {
        int s = i % PF;
        const unsigned short* ap = a2 + ((size_t)i << 12);
        const unsigned short* bp = b2 + ((size_t)i << 12);
        fA[s][0] = LD8(ap);
        fA[s][1] = LD8(ap + (64 << 9));
        fA[s][2] = LD8(ap + 2 * (64 << 9));
        fA[s][3] = LD8(ap + 3 * (64 << 9));
        fB[s][0] = LD8(bp);
        fB[s][1] = LD8(bp + (64 << 9));
    };
    #pragma unroll
    for (int i = 0; i < PF; ++i) issue(i);
    if (s1) {
        #pragma unroll
        for (int mi = 0; mi < 4; ++mi)
            #pragma unroll
            for (int p = 0; p < 2; ++p)
                acc[mi][p] = __builtin_amdgcn_mfma_f32_16x16x32_bf16(xa[mi], xw[p], acc[mi][p], 0, 0, 0);
    }
    #pragma unroll
    for (int i = 0; i < NC; ++i) {
        int s = i % PF;
        #pragma unroll
        for (int mi = 0; mi < 4; ++mi)
            #pragma unroll
            for (int p = 0; p < 2; ++p)
                acc[mi][p] = __builtin_amdgcn_mfma_f32_16x16x32_bf16(fA[s][mi], fB[s][p], acc[mi][p], 0, 0, 0);
        if (i + PF < NC) issue(i + PF);
    }

    // ---- epilogue: K-slice reduce + cell update
    int n15 = lane & 15, quad = lane >> 4;
    #pragma unroll
    for (int mi = 0; mi < 4; ++mi)
        #pragma unroll
        for (int p = 0; p < 2; ++p)
            #pragma unroll
            for (int r = 0; r < 4; ++r) {
                int R = mi * 16 + quad * 4 + r;
                int C = p * 16 + n15;
                gsm[w][R][C ^ ((R & 3) << 3)] = acc[mi][p][r];
            }
    __syncthreads();
    int b = tid >> 3, jj = tid & 7;
    float g4[4];
    #pragma unroll
    for (int g = 0; g < 4; ++g) {
        int Cp = (g * 8 + jj) ^ ((b & 3) << 3);
        float s = 0.f;
        #pragma unroll
        for (int w8 = 0; w8 < 8; ++w8) s += gsm[w8][b][Cp];
        g4[g] = s;
    }
    int j = jb * 8 + jj;
    float iv = 1.f / (1.f + __expf(-(g4[0] + bsum[j])));
    float fv = 1.f / (1.f + __expf(-(g4[1] + bsum[2048 + j])));
    float gv = tanhf(g4[2] + bsum[4096 + j]);
    float ov = 1.f / (1.f + __expf(-(g4[3] + bsum[6144 + j])));
    float cn = fv * c_state[jb * 512 + tid] + iv * gv;
    float hn = ov * tanhf(cn);
    c_state[jb * 512 + tid] = cn;
    h_out[ap_idx(b, j, 64)] = f2bf(hn);
}

// --------------------------- layer 1 + FC partial --------------------------
__global__ __launch_bounds__(512, 2) void lstm_l1(
        const unsigned short* __restrict__ Ap1,  // h0 new, Ap KC=64
        const unsigned short* __restrict__ Bp1,  // wih1p
        const unsigned short* __restrict__ Ap2,  // h1 prev
        const unsigned short* __restrict__ Bp2,  // whh1p
        const float* __restrict__ bsum,
        float* __restrict__ c_state,
        unsigned short* __restrict__ h_out,
        const float* __restrict__ fcw,           // fp32 [66][2048]
        float* __restrict__ ows_t) {             // out_ws[t] ([66][64])
    __shared__ float gsm[8][64][32];
    int tid = threadIdx.x, lane = tid & 63, w = tid >> 6;
    int jb = blockIdx.x;
    constexpr int PF = 3, NC = 16;
    const unsigned short* a1 = Ap1 + ((size_t)w << 9) + lane * 8;
    const unsigned short* b1 = Bp1 + (((size_t)(2 * jb) * 64 + w) << 9) + lane * 8;
    const unsigned short* a2 = Ap2 + ((size_t)w << 9) + lane * 8;
    const unsigned short* b2 = Bp2 + (((size_t)(2 * jb) * 64 + w) << 9) + lane * 8;
    accv acc[4][2] = {};
    bfrag fA[PF][4], fB[PF][2];
    auto issue = [&](int i) {
        int s = i % PF;
        const unsigned short *ap, *bp;
        if (i < 8) { ap = a1 + ((size_t)i << 12); bp = b1 + ((size_t)i << 12); }
        else       { ap = a2 + ((size_t)(i - 8) << 12); bp = b2 + ((size_t)(i - 8) << 12); }
        fA[s][0] = LD8(ap);
        fA[s][1] = LD8(ap + (64 << 9));
        fA[s][2] = LD8(ap + 2 * (64 << 9));
        fA[s][3] = LD8(ap + 3 * (64 << 9));
        fB[s][0] = LD8(bp);
        fB[s][1] = LD8(bp + (64 << 9));
    };
    #pragma unroll
    for (int i = 0; i < PF; ++i) issue(i);
    #pragma unroll
    for (int i = 0; i < NC; ++i) {
        int s = i % PF;
        #pragma unroll
        for (int mi = 0; mi < 4; ++mi)
            #pragma unroll
            for (int p = 0; p < 2; ++p)
                acc[mi][p] = __builtin_amdgcn_mfma_f32_16x16x32_bf16(fA[s][mi], fB[s][p], acc[mi][p], 0, 0, 0);
        if (i + PF < NC) issue(i + PF);
    }

    int n15 = lane & 15, quad = lane >> 4;
    #pragma unroll
    for (int mi = 0; mi < 4; ++mi)
        #pragma unroll
        for (int p = 0; p < 2; ++p)
            #pragma unroll
            for (int r = 0; r < 4; ++r) {
                int R = mi * 16 + quad * 4 + r;
                int C = p * 16 + n15;
                gsm[w][R][C ^ ((R & 3) << 3)] = acc[mi][p][r];
            }
    __syncthreads();
    int b = tid >> 3, jj = tid & 7;
    float g4[4];
    #pragma unroll
    for (int g = 0; g < 4; ++g) {
        int Cp = (g * 8 + jj) ^ ((b & 3) << 3);
        float s = 0.f;
        #pragma unroll
        for (int w8 = 0; w8 < 8; ++w8) s += gsm[w8][b][Cp];
        g4[g] = s;
    }
    int j = jb * 8 + jj;
    float iv = 1.f / (1.f + __expf(-(g4[0] + bsum[j])));
    float fv = 1.f / (1.f + __expf(-(g4[1] + bsum[2048 + j])));
    float gv = tanhf(g4[2] + bsum[4096 + j]);
    float ov = 1.f / (1.f + __expf(-(g4[3] + bsum[6144 + j])));
    float cn = fv * c_state[jb * 512 + tid] + iv * gv;
    float hn = ov * tanhf(cn);
    c_state[jb * 512 + tid] = cn;
    h_out[ap_idx(b, j, 64)] = f2bf(hn);

    // ---- FC partial: out_part[o][b] += h[b][jb*8..+8] . fcw[o][jb*8..+8]
    __syncthreads();                             // gsm reads done; reuse as hsm
    float* hs = &gsm[0][0][0];                   // [64][9] padded
    hs[b * 9 + jj] = hn;                         // fp32 h (pre-bf16-rounding)
    __syncthreads();
    for (int idx = tid; idx < 4224; idx += 512) {
        int o = idx >> 6, b2 = idx & 63;
        const float* wc = fcw + (size_t)o * 2048 + jb * 8;
        float s = 0.f;
        #pragma unroll
        for (int q = 0; q < 8; ++q) s = fmaf(hs[b2 * 9 + q], wc[q], s);
        atomicAdd(ows_t + idx, s);
    }
}

// --------------------------- final FC output (t=24) ------------------------
__global__ __launch_bounds__(256) void finalize(
        const float* __restrict__ ows24, const float* __restrict__ fcb,
        float* __restrict__ outg) {
    int idx = blockIdx.x * 256 + threadIdx.x;
    if (idx < 4224) {
        int o = idx >> 6, b = idx & 63;
        float v = ows24[idx] + fcb[o];
        v = fminf(1.f, fmaxf(-1.f, v));
        outg[((size_t)b * 25 + 24) * 66 + o] = v;
    }
}

// ---------------------------------------------------------------------------
extern "C" void kernel_launch(void* const* d_in, const int* in_sizes, int n_in,
                              void* d_out, int out_size, void* d_ws, size_t ws_size,
                              hipStream_t stream) {
    (void)in_sizes; (void)n_in; (void)out_size; (void)ws_size;
    const float* inputs  = (const float*)d_in[0];
    const float* hiddens = (const float*)d_in[1];
    const float* cells   = (const float*)d_in[2];
    const float* W_ih0   = (const float*)d_in[3];
    const float* W_hh0   = (const float*)d_in[4];
    const float* b_ih0   = (const float*)d_in[5];
    const float* b_hh0   = (const float*)d_in[6];
    const float* W_ih1   = (const float*)d_in[7];
    const float* W_hh1   = (const float*)d_in[8];
    const float* b_ih1   = (const float*)d_in[9];
    const float* b_hh1   = (const float*)d_in[10];
    const float* fc_w    = (const float*)d_in[11];
    const float* fc_b    = (const float*)d_in[12];
    float* out = (float*)d_out;

    // workspace layout (~104.8 MB)
    unsigned short* whh0p = (unsigned short*)d_ws;     // 16777216 shorts each
    unsigned short* wih1p = whh0p + 16777216;
    unsigned short* whh1p = wih1p + 16777216;
    unsigned short* wih0p = whh1p + 16777216;          // 786432 (Bp KC=3)
    unsigned short* h0a   = wih0p + 786432;            // 131072 each (Ap KC=64)
    unsigned short* h0b   = h0a + 131072;
    unsigned short* h1a   = h0b + 131072;
    unsigned short* h1b   = h1a + 131072;
    unsigned short* xb    = h1b + 131072;              // 6144 (Ap KC=3)
    float* c0    = (float*)(xb + 6144);                // 131072 fp32 each
    float* c1    = c0 + 131072;
    float* bsum0 = c1 + 131072;                        // 8192 fp32 each
    float* bsum1 = bsum0 + 8192;
    float* ows   = bsum1 + 8192;                       // 25 x 4224 fp32

    prep<<<30198, 256, 0, stream>>>(W_hh0, W_ih1, W_hh1, whh0p, wih1p, whh1p,
                                    inputs, hiddens, cells, W_ih0,
                                    wih0p, h0a, h1a, c0, c1, xb,
                                    bsum0, bsum1, b_ih0, b_hh0, b_ih1, b_hh1, ows);

    unsigned short* h0buf[2] = {h0a, h0b};
    unsigned short* h1buf[2] = {h1a, h1b};
    for (int t = 0; t < 25; ++t) {
        int cur = t & 1, nxt = cur ^ 1;
        lstm_l0<<<256, 512, 0, stream>>>(xb, wih0p, h0buf[cur], whh0p, bsum0,
                                         t == 0 ? (const float*)nullptr : ows + (t - 1) * 4224,
                                         fc_b, out, t - 1, c0, h0buf[nxt]);
        lstm_l1<<<256, 512, 0, stream>>>(h0buf[nxt], wih1p, h1buf[cur], whh1p, bsum1,
                                         c1, h1buf[nxt], fc_w, ows + t * 4224);
    }
    finalize<<<17, 256, 0, stream>>>(ows + 24 * 4224, fc_b, out);
}

// Round 5
// 953.083 us; speedup vs baseline: 1.1857x; 1.1857x over previous
//
#include <hip/hip_runtime.h>
#include <hip/hip_bf16.h>

// ---------------------------------------------------------------------------
// 2-layer LSTM decoder, B=64, T=25, H=2048, IN=OUT=66, hardtanh feedback.
// v5: per step, recurrent GEMMs (h0@Whh0, h1@Whh1) + FC(h1) all depend only
// on step t-1 state -> computed together in one wide kernel P (578 blocks,
// 2/CU). Serial path is only C0 (x@Wih0, tiny) and C1 (h0@Wih1). All GEMM
// loops use the v3-proven NC=8/PF=2/(512,4) shape (88 VGPR, 2 blocks/CU).
// ---------------------------------------------------------------------------

typedef short bfrag  __attribute__((ext_vector_type(8)));   // 8 bf16 (4 VGPR)
typedef float accv   __attribute__((ext_vector_type(4)));   // 4 fp32 acc
typedef float vfloat4 __attribute__((ext_vector_type(4)));
typedef unsigned short usvec8 __attribute__((ext_vector_type(8)));

#define LD8(p) (*(const bfrag*)(p))

__device__ __forceinline__ unsigned short f2bf(float x) {
    unsigned int u = __float_as_uint(x);
    unsigned int r = u + 0x7FFFu + ((u >> 16) & 1u);   // RTNE
    return (unsigned short)(r >> 16);
}
__device__ __forceinline__ float bf2f(unsigned short u) {
    return __uint_as_float(((unsigned int)u) << 16);
}

// Activation fragment layout ("Ap", KC chunks of 32 k-elements):
//   (b, k) -> [((b>>4)*KC + (k>>5))*512 + (((k>>3)&3)*16 + (b&15))*8 + (k&7)]
__device__ __forceinline__ int ap_idx(int b, int j, int KC) {
    return (((b >> 4) * KC + (j >> 5)) << 9) + ((((j >> 3) & 3) * 16 + (b & 15)) << 3) + (j & 7);
}

// Weight fragment layout ("Bp"): n-tile (jb,p) holds rows
//   row = (2p + (n>>3))*2048 + jb*8 + (n&7),  n = lane&15
//   element at [((jb*2+p)*KC + kc)*512 + lane*8 + j],  k = kc*32 + (lane>>4)*8 + j

// ------------------- combined weight cast + state init ---------------------
__global__ __launch_bounds__(256) void prep(
        const float* __restrict__ s0, const float* __restrict__ s1, const float* __restrict__ s2,
        unsigned short* __restrict__ d0, unsigned short* __restrict__ d1, unsigned short* __restrict__ d2,
        const float* __restrict__ inputs, const float* __restrict__ hiddens,
        const float* __restrict__ cells,  const float* __restrict__ wih0,
        unsigned short* __restrict__ wih0p,
        unsigned short* __restrict__ h0, unsigned short* __restrict__ h1,
        float* __restrict__ c0, float* __restrict__ c1,
        unsigned short* __restrict__ xb,
        float* __restrict__ bsum0, float* __restrict__ bsum1,
        const float* __restrict__ bih0, const float* __restrict__ bhh0,
        const float* __restrict__ bih1, const float* __restrict__ bhh1) {
    int bid = blockIdx.x;
    if (bid < 24576) {                       // big-weight cast+permute
        unsigned int tid = bid * 256 + threadIdx.x;     // 0 .. 6291455
        unsigned int a = tid >> 21;                     // 2097152 frags per matrix
        unsigned int r = tid & 2097151u;
        const float* src = (a == 0) ? s0 : (a == 1) ? s1 : s2;
        unsigned short* dst = (a == 0) ? d0 : (a == 1) ? d1 : d2;
        unsigned int lane = r & 63u;
        unsigned int kc   = (r >> 6) & 63u;
        unsigned int p    = (r >> 12) & 1u;
        unsigned int jb   = r >> 13;
        unsigned int n = lane & 15u, quad = lane >> 4;
        unsigned int row = (2u * p + (n >> 3)) * 2048u + jb * 8u + (n & 7u);
        unsigned int k0  = kc * 32u + quad * 8u;
        const float* sp = src + (size_t)row * 2048 + k0;
        vfloat4 v0 = *(const vfloat4*)sp;
        vfloat4 v1 = *(const vfloat4*)(sp + 4);
        usvec8 u = { f2bf(v0.x), f2bf(v0.y), f2bf(v0.z), f2bf(v0.w),
                     f2bf(v1.x), f2bf(v1.y), f2bf(v1.z), f2bf(v1.w) };
        *(usvec8*)(dst + (size_t)r * 8) = u;
        return;
    }
    int i = (bid - 24576) * 256 + threadIdx.x;
    if (i < 786432) {                        // Wih0 pad-permute: [8192][66] -> Bp KC=3
        int jo = i & 7, lane = (i >> 3) & 63;
        int t2 = i >> 9, kc = t2 % 3, t3 = t2 / 3, p = t3 & 1, jb = t3 >> 1;
        int n = lane & 15, quad = lane >> 4;
        int row = (2 * p + (n >> 3)) * 2048 + jb * 8 + (n & 7);
        int k = kc * 32 + quad * 8 + jo;
        wih0p[i] = (k < 66) ? f2bf(wih0[row * 66 + k]) : (unsigned short)0;
        return;
    }
    i -= 786432;
    if (i < 131072) { int b = i >> 11, j = i & 2047; h0[ap_idx(b, j, 64)] = f2bf(hiddens[i]); return; }
    i -= 131072;
    if (i < 131072) { int b = i >> 11, j = i & 2047; h1[ap_idx(b, j, 64)] = f2bf(hiddens[131072 + i]); return; }
    i -= 131072;
    if (i < 131072) { int b = i >> 11, j = i & 2047; c0[(j >> 3) * 512 + b * 8 + (j & 7)] = cells[i]; return; }
    i -= 131072;
    if (i < 131072) { int b = i >> 11, j = i & 2047; c1[(j >> 3) * 512 + b * 8 + (j & 7)] = cells[131072 + i]; return; }
    i -= 131072;
    if (i < 6144) {                          // x pad-permute -> Ap KC=3
        int jo = i & 7, lane = (i >> 3) & 63;
        int t2 = i >> 9, kc = t2 % 3, m = t2 / 3;
        int b = m * 16 + (lane & 15);
        int k = kc * 32 + (lane >> 4) * 8 + jo;
        xb[i] = (k < 66) ? f2bf(inputs[b * 66 + k]) : (unsigned short)0;
        return;
    }
    i -= 6144;
    if (i < 8192) { bsum0[i] = bih0[i] + bhh0[i]; return; }
    i -= 8192;
    if (i < 8192) { bsum1[i] = bih1[i] + bhh1[i]; }
}

// ---------------- shared GEMM body: 8 chunks/wave, PF=2, KC=64 -------------
__device__ __forceinline__ void gemm8(const unsigned short* __restrict__ Ap,
                                      const unsigned short* __restrict__ Bp,
                                      int jb, int lane, int w, accv (&acc)[4][2]) {
    constexpr int PF = 2, NC = 8;
    const unsigned short* a = Ap + ((size_t)w << 9) + lane * 8;
    const unsigned short* b = Bp + (((size_t)(2 * jb) * 64 + w) << 9) + lane * 8;
    bfrag fA[PF][4], fB[PF][2];
    auto issue = [&](int i) {
        int s = i % PF;
        const unsigned short* ap = a + ((size_t)i << 12);   // +8 chunks
        const unsigned short* bp = b + ((size_t)i << 12);
        fA[s][0] = LD8(ap);
        fA[s][1] = LD8(ap + (64 << 9));
        fA[s][2] = LD8(ap + 2 * (64 << 9));
        fA[s][3] = LD8(ap + 3 * (64 << 9));
        fB[s][0] = LD8(bp);
        fB[s][1] = LD8(bp + (64 << 9));
    };
    #pragma unroll
    for (int i = 0; i < PF; ++i) issue(i);
    #pragma unroll
    for (int i = 0; i < NC; ++i) {
        int s = i % PF;
        #pragma unroll
        for (int mi = 0; mi < 4; ++mi)
            #pragma unroll
            for (int p = 0; p < 2; ++p)
                acc[mi][p] = __builtin_amdgcn_mfma_f32_16x16x32_bf16(fA[s][mi], fB[s][p], acc[mi][p], 0, 0, 0);
        if (i + PF < NC) issue(i + PF);
    }
}

__device__ __forceinline__ void store_gsm(float (*gsm)[64][32], accv (&acc)[4][2],
                                          int lane, int w) {
    int n = lane & 15, quad = lane >> 4;
    #pragma unroll
    for (int mi = 0; mi < 4; ++mi)
        #pragma unroll
        for (int p = 0; p < 2; ++p)
            #pragma unroll
            for (int r = 0; r < 4; ++r) {
                int R = mi * 16 + quad * 4 + r;          // batch
                int C = p * 16 + n;                      // gate*8 + unit
                gsm[w][R][C ^ ((R & 3) << 3)] = acc[mi][p][r];
            }
}

// --------------------------- P: parallel pre-step --------------------------
// blocks 0..65: FC from h1[t-1] -> out[t-1], x_t (skipped at t==0).
// blocks 66..321: layer0 recurrent partial (h0 @ Whh0^T) -> gp0.
// blocks 322..577: layer1 recurrent partial (h1 @ Whh1^T) -> gp1.
__global__ __launch_bounds__(512, 4) void pstep(
        const unsigned short* __restrict__ h0, const unsigned short* __restrict__ h1,
        const unsigned short* __restrict__ Bp0, const unsigned short* __restrict__ Bp1,
        const float* __restrict__ fcw, const float* __restrict__ fcb,
        float* __restrict__ gp0, float* __restrict__ gp1,   // [256][2048] fp32
        unsigned short* __restrict__ xbuf,                  // Ap KC=3
        float* __restrict__ outg, int t) {
    __shared__ float gsm[8][64][32];
    int tid = threadIdx.x, lane = tid & 63, w = tid >> 6;
    int bid = blockIdx.x;

    if (bid < 66) {                          // ---- FC section
        if (t == 0) return;
        int o = bid, b = lane;
        const float* wrow = fcw + (size_t)o * 2048;
        float acc = 0.f;
        for (int kc = w; kc < 64; kc += 8) {
            const unsigned short* hp = h1 + (((size_t)(b >> 4) * 64 + kc) << 9) + (b & 15) * 8;
            const float* wp = wrow + kc * 32;
            #pragma unroll
            for (int q = 0; q < 4; ++q) {
                usvec8 hv = *(const usvec8*)(hp + q * 128);
                vfloat4 w0 = *(const vfloat4*)(wp + q * 8);
                vfloat4 w1 = *(const vfloat4*)(wp + q * 8 + 4);
                acc = fmaf(bf2f(hv[0]), w0.x, acc);
                acc = fmaf(bf2f(hv[1]), w0.y, acc);
                acc = fmaf(bf2f(hv[2]), w0.z, acc);
                acc = fmaf(bf2f(hv[3]), w0.w, acc);
                acc = fmaf(bf2f(hv[4]), w1.x, acc);
                acc = fmaf(bf2f(hv[5]), w1.y, acc);
                acc = fmaf(bf2f(hv[6]), w1.z, acc);
                acc = fmaf(bf2f(hv[7]), w1.w, acc);
            }
        }
        float* red = &gsm[0][0][0];          // reuse LDS as [8][64]
        red[w * 64 + b] = acc;
        __syncthreads();
        if (tid < 64) {
            int bb = tid;
            float v = fcb[o];
            #pragma unroll
            for (int q = 0; q < 8; ++q) v += red[q * 64 + bb];
            v = fminf(1.f, fmaxf(-1.f, v));
            outg[((size_t)bb * 25 + (t - 1)) * 66 + o] = v;
            xbuf[ap_idx(bb, o, 3)] = f2bf(v);
        }
        return;
    }

    // ---- recurrent GEMM partial
    int l  = (bid - 66) >> 8;
    int jb = (bid - 66) & 255;
    const unsigned short* Ap = l ? h1 : h0;
    const unsigned short* Bp = l ? Bp1 : Bp0;
    float* gp = l ? gp1 : gp0;
    accv acc[4][2] = {};
    gemm8(Ap, Bp, jb, lane, w, acc);
    store_gsm(gsm, acc, lane, w);
    __syncthreads();
    for (int idx = tid; idx < 2048; idx += 512) {
        int b = idx >> 5, C = idx & 31;
        int Cs = C ^ ((b & 3) << 3);
        float s = 0.f;
        #pragma unroll
        for (int w8 = 0; w8 < 8; ++w8) s += gsm[w8][b][Cs];
        gp[(size_t)jb * 2048 + idx] = s;
    }
}

// --------------------------- C0: x-GEMM + cell0 ----------------------------
__global__ __launch_bounds__(512, 4) void c0step(
        const unsigned short* __restrict__ xbuf, const unsigned short* __restrict__ Bp, // wih0p KC=3
        const float* __restrict__ gp0, const float* __restrict__ bsum,
        float* __restrict__ c_state, unsigned short* __restrict__ h_out) {
    __shared__ float gsm[8][64][32];
    int tid = threadIdx.x, lane = tid & 63, w = tid >> 6;
    int jb = blockIdx.x;
    accv acc[4][2] = {};
    if (w < 3) {
        const unsigned short* bp = Bp + (((size_t)(2 * jb) * 3 + w) << 9) + lane * 8;
        bfrag xw0 = LD8(bp), xw1 = LD8(bp + (3 << 9));
        #pragma unroll
        for (int mi = 0; mi < 4; ++mi) {
            bfrag xa = LD8(xbuf + (((size_t)mi * 3 + w) << 9) + lane * 8);
            acc[mi][0] = __builtin_amdgcn_mfma_f32_16x16x32_bf16(xa, xw0, acc[mi][0], 0, 0, 0);
            acc[mi][1] = __builtin_amdgcn_mfma_f32_16x16x32_bf16(xa, xw1, acc[mi][1], 0, 0, 0);
        }
    }
    store_gsm(gsm, acc, lane, w);            // waves >=3 store zeros
    __syncthreads();
    int b = tid >> 3, jj = tid & 7;
    const float* gpt = gp0 + (size_t)jb * 2048 + b * 32 + jj;
    float g4[4];
    #pragma unroll
    for (int g = 0; g < 4; ++g) {
        int Cp = (g * 8 + jj) ^ ((b & 3) << 3);
        float s = gpt[g * 8];
        #pragma unroll
        for (int w8 = 0; w8 < 8; ++w8) s += gsm[w8][b][Cp];
        g4[g] = s;
    }
    int j = jb * 8 + jj;
    float iv = 1.f / (1.f + __expf(-(g4[0] + bsum[j])));
    float fv = 1.f / (1.f + __expf(-(g4[1] + bsum[2048 + j])));
    float gv = tanhf(g4[2] + bsum[4096 + j]);
    float ov = 1.f / (1.f + __expf(-(g4[3] + bsum[6144 + j])));
    float cn = fv * c_state[jb * 512 + tid] + iv * gv;
    float hn = ov * tanhf(cn);
    c_state[jb * 512 + tid] = cn;
    h_out[ap_idx(b, j, 64)] = f2bf(hn);
}

// --------------------------- C1: h0-GEMM + cell1 ---------------------------
__global__ __launch_bounds__(512, 4) void c1step(
        const unsigned short* __restrict__ h0new, const unsigned short* __restrict__ Bp, // wih1p
        const float* __restrict__ gp1, const float* __restrict__ bsum,
        float* __restrict__ c_state, unsigned short* __restrict__ h_out) {
    __shared__ float gsm[8][64][32];
    int tid = threadIdx.x, lane = tid & 63, w = tid >> 6;
    int jb = blockIdx.x;
    accv acc[4][2] = {};
    gemm8(h0new, Bp, jb, lane, w, acc);
    store_gsm(gsm, acc, lane, w);
    __syncthreads();
    int b = tid >> 3, jj = tid & 7;
    const float* gpt = gp1 + (size_t)jb * 2048 + b * 32 + jj;
    float g4[4];
    #pragma unroll
    for (int g = 0; g < 4; ++g) {
        int Cp = (g * 8 + jj) ^ ((b & 3) << 3);
        float s = gpt[g * 8];
        #pragma unroll
        for (int w8 = 0; w8 < 8; ++w8) s += gsm[w8][b][Cp];
        g4[g] = s;
    }
    int j = jb * 8 + jj;
    float iv = 1.f / (1.f + __expf(-(g4[0] + bsum[j])));
    float fv = 1.f / (1.f + __expf(-(g4[1] + bsum[2048 + j])));
    float gv = tanhf(g4[2] + bsum[4096 + j]);
    float ov = 1.f / (1.f + __expf(-(g4[3] + bsum[6144 + j])));
    float cn = fv * c_state[jb * 512 + tid] + iv * gv;
    float hn = ov * tanhf(cn);
    c_state[jb * 512 + tid] = cn;
    h_out[ap_idx(b, j, 64)] = f2bf(hn);
}

// ---------------------------------------------------------------------------
extern "C" void kernel_launch(void* const* d_in, const int* in_sizes, int n_in,
                              void* d_out, int out_size, void* d_ws, size_t ws_size,
                              hipStream_t stream) {
    (void)in_sizes; (void)n_in; (void)out_size; (void)ws_size;
    const float* inputs  = (const float*)d_in[0];
    const float* hiddens = (const float*)d_in[1];
    const float* cells   = (const float*)d_in[2];
    const float* W_ih0   = (const float*)d_in[3];
    const float* W_hh0   = (const float*)d_in[4];
    const float* b_ih0   = (const float*)d_in[5];
    const float* b_hh0   = (const float*)d_in[6];
    const float* W_ih1   = (const float*)d_in[7];
    const float* W_hh1   = (const float*)d_in[8];
    const float* b_ih1   = (const float*)d_in[9];
    const float* b_hh1   = (const float*)d_in[10];
    const float* fc_w    = (const float*)d_in[11];
    const float* fc_b    = (const float*)d_in[12];
    float* out = (float*)d_out;

    // workspace layout (~108 MB)
    unsigned short* whh0p = (unsigned short*)d_ws;     // 16777216 shorts each
    unsigned short* wih1p = whh0p + 16777216;
    unsigned short* whh1p = wih1p + 16777216;
    unsigned short* wih0p = whh1p + 16777216;          // 786432 (Bp KC=3)
    unsigned short* h0    = wih0p + 786432;            // 131072 (Ap KC=64), in-place
    unsigned short* h1    = h0 + 131072;
    unsigned short* xb    = h1 + 131072;               // 6144 (Ap KC=3)
    float* c0    = (float*)(xb + 6144);                // 131072 fp32 each
    float* c1    = c0 + 131072;
    float* bsum0 = c1 + 131072;                        // 8192 fp32 each
    float* bsum1 = bsum0 + 8192;
    float* gp0   = bsum1 + 8192;                       // 524288 fp32 each (2 MB)
    float* gp1   = gp0 + 524288;

    prep<<<29784, 256, 0, stream>>>(W_hh0, W_ih1, W_hh1, whh0p, wih1p, whh1p,
                                    inputs, hiddens, cells, W_ih0,
                                    wih0p, h0, h1, c0, c1, xb,
                                    bsum0, bsum1, b_ih0, b_hh0, b_ih1, b_hh1);

    for (int t = 0; t < 25; ++t) {
        pstep<<<578, 512, 0, stream>>>(h0, h1, whh0p, whh1p, fc_w, fc_b,
                                       gp0, gp1, xb, out, t);
        c0step<<<256, 512, 0, stream>>>(xb, wih0p, gp0, bsum0, c0, h0);
        c1step<<<256, 512, 0, stream>>>(h0, wih1p, gp1, bsum1, c1, h1);
    }
    // final FC (out[24]) from h1_24: reuse pstep's FC section only
    pstep<<<66, 512, 0, stream>>>(h0, h1, whh0p, whh1p, fc_w, fc_b,
                                  gp0, gp1, xb, out, 25);
}